// Round 10
// baseline (2715.028 us; speedup 1.0000x reference)
//
#include <hip/hip_runtime.h>

// ---------------------------------------------------------------------------
// VQEmbeddingEMA forward on MI355X (gfx950), fp32.
//   N = 32*2048 = 65536 tokens, D = 64, K = 1024 codes.
// Round 10: e stays per-lane in registers; x delivered via LDS broadcast
// (32KB tile staged coalesced, ds_read_b128 wave-uniform = conflict-free
// broadcast, 1 read : 4 FMA : 64 lanes). 4 tokens in flight (4 indep FMA
// chains). Parts XCD-co-located (blk = part*512+grp, 512%8==0) -> x HBM-
// fetched once (round 9: 4x = 66MB). launch_bounds(256,4): VGPR cap 128,
// body ~90, cannot spill (round-8 lesson).
// ---------------------------------------------------------------------------

#define N_TOK   65536
#define KCODES  1024

#define Q_OFF   0
#define SC_OFF  4194304
#define NE_OFF  4194307
#define NC_OFF  4259843
#define NW_OFF  4260867
#define NU_OFF  4326403

// ws layout (floats)
#define WS_COUNTS 0              // [1024]  (atomic, zeroed)
#define WS_LOSS   1024           // [1]     (atomic, zeroed)
#define WS_IDX    1028           // [65536] int
#define WS_PS     66564          // [4][65536] partial scores
#define WS_PI     328708         // [4][65536] partial indices (int)

// Lane l of wave w owns code part*256 + w*64 + l (e in VGPRs, loaded once).
// Block stages 128 tokens of x in LDS; each wave scans all 128 tokens.
__global__ __launch_bounds__(256, 4) void assign_kernel(
    const float* __restrict__ x, const float* __restrict__ emb,
    float* __restrict__ pscore, int* __restrict__ pidx) {
    const int part = blockIdx.x >> 9;      // 0..3   (256 codes per part)
    const int grp  = blockIdx.x & 511;     // 0..511 (128 tokens per group)
    const int tid  = threadIdx.x;
    const int wid  = tid >> 6;             // 0..3
    const int lane = tid & 63;
    const int code = part * 256 + wid * 64 + lane;

    // e row for this lane's code -> VGPRs (all indices static after unroll).
    const float4* __restrict__ e4 =
        reinterpret_cast<const float4*>(emb) + (size_t)code * 16;
    float er[64];
#pragma unroll
    for (int i = 0; i < 16; ++i) {
        float4 v = e4[i];
        er[4 * i + 0] = v.x; er[4 * i + 1] = v.y;
        er[4 * i + 2] = v.z; er[4 * i + 3] = v.w;
    }
    float hn = 0.0f;
#pragma unroll
    for (int i = 0; i < 64; ++i) hn = fmaf(er[i], er[i], hn);
    hn *= 0.5f;

    __shared__ float4 sx4[2048];          // 128 tokens x 64 floats = 32 KB
    __shared__ float  cs[4][128];
    __shared__ int    ci[4][128];

    // coalesced stage: 2048 float4 / 256 threads = 8 iters
    const float4* __restrict__ gx4 =
        reinterpret_cast<const float4*>(x) + (size_t)grp * 2048;
#pragma unroll
    for (int i = 0; i < 8; ++i) sx4[i * 256 + tid] = gx4[i * 256 + tid];
    __syncthreads();

    for (int tg = 0; tg < 32; ++tg) {     // 4 tokens per iteration
        const int t0 = tg * 4;
        float a0 = 0.f, a1 = 0.f, a2 = 0.f, a3 = 0.f;
#pragma unroll
        for (int i = 0; i < 16; ++i) {
            // wave-uniform addresses -> ds_read_b128 broadcast, no conflicts
            float4 x0 = sx4[(t0 + 0) * 16 + i];
            float4 x1 = sx4[(t0 + 1) * 16 + i];
            float4 x2 = sx4[(t0 + 2) * 16 + i];
            float4 x3 = sx4[(t0 + 3) * 16 + i];
            a0 = fmaf(x0.x, er[4*i+0], a0); a0 = fmaf(x0.y, er[4*i+1], a0);
            a0 = fmaf(x0.z, er[4*i+2], a0); a0 = fmaf(x0.w, er[4*i+3], a0);
            a1 = fmaf(x1.x, er[4*i+0], a1); a1 = fmaf(x1.y, er[4*i+1], a1);
            a1 = fmaf(x1.z, er[4*i+2], a1); a1 = fmaf(x1.w, er[4*i+3], a1);
            a2 = fmaf(x2.x, er[4*i+0], a2); a2 = fmaf(x2.y, er[4*i+1], a2);
            a2 = fmaf(x2.z, er[4*i+2], a2); a2 = fmaf(x2.w, er[4*i+3], a2);
            a3 = fmaf(x3.x, er[4*i+0], a3); a3 = fmaf(x3.y, er[4*i+1], a3);
            a3 = fmaf(x3.z, er[4*i+2], a3); a3 = fmaf(x3.w, er[4*i+3], a3);
        }
#pragma unroll
        for (int j = 0; j < 4; ++j) {
            float s = hn - ((j == 0) ? a0 : (j == 1) ? a1 : (j == 2) ? a2 : a3);
            // 64-lane min-reduce; tie -> lowest lane = lowest code (jnp)
            float m = s;
#pragma unroll
            for (int off = 32; off; off >>= 1)
                m = fminf(m, __shfl_xor(m, off, 64));
            unsigned long long bal = __ballot(s == m);
            int first = __ffsll((long long)bal) - 1;
            if (lane == first) { cs[wid][t0 + j] = s; ci[wid][t0 + j] = code; }
        }
    }
    __syncthreads();

    if (tid < 128) {
        float bs = cs[0][tid];
        int   bi = ci[0][tid];
#pragma unroll
        for (int w = 1; w < 4; ++w) {
            float s2 = cs[w][tid];
            int   i2 = ci[w][tid];
            if (s2 < bs) { bs = s2; bi = i2; }  // ascending w = ascending code
        }
        pscore[part * N_TOK + grp * 128 + tid] = bs;
        pidx  [part * N_TOK + grp * 128 + tid] = bi;
    }
}

// Combine 4 partial candidates; write idx, quantized, loss, counts.
__global__ __launch_bounds__(256) void merge_kernel(
    const float* __restrict__ x, const float* __restrict__ emb,
    const float* __restrict__ pscore, const int* __restrict__ pidx,
    float* __restrict__ counts, int* __restrict__ idx,
    float* __restrict__ loss_sum, float* __restrict__ qout) {
    const int tok = blockIdx.x * 256 + threadIdx.x;

    float bs = pscore[tok];
    int   bi = pidx[tok];
#pragma unroll
    for (int h = 1; h < 4; ++h) {
        float s  = pscore[h * N_TOK + tok];
        int   i2 = pidx[h * N_TOK + tok];
        // later h always has larger idx, so strict < keeps lowest-idx min
        if (s < bs) { bs = s; bi = i2; }
    }
    idx[tok] = bi;

    const float4* x4  = reinterpret_cast<const float4*>(x) + (size_t)tok * 16;
    const float4* eb4 = reinterpret_cast<const float4*>(emb) + (size_t)bi * 16;
    float4* q4 = reinterpret_cast<float4*>(qout) + (size_t)tok * 16;

    float lsum = 0.0f;
#pragma unroll
    for (int i = 0; i < 16; ++i) {
        float4 xv = x4[i];
        float4 e  = eb4[i];
        q4[i] = e;
        float d0 = xv.x - e.x; lsum = fmaf(d0, d0, lsum);
        float d1 = xv.y - e.y; lsum = fmaf(d1, d1, lsum);
        float d2 = xv.z - e.z; lsum = fmaf(d2, d2, lsum);
        float d3 = xv.w - e.w; lsum = fmaf(d3, d3, lsum);
    }

    atomicAdd(&counts[bi], 1.0f);

#pragma unroll
    for (int off = 32; off; off >>= 1) lsum += __shfl_down(lsum, off, 64);
    if ((threadIdx.x & 63) == 0) atomicAdd(loss_sum, lsum);
}

// counts-based outputs: new_count, new_usage, scalars (one block, k = tid).
// Runs BEFORE gather (gather reads out[NC_OFF+k]).
__global__ __launch_bounds__(1024) void finalize1(
    const float* __restrict__ counts, const float* __restrict__ loss_sum,
    const float* __restrict__ ema_count, const float* __restrict__ usage,
    float* __restrict__ out) {
    const int k = threadIdx.x;
    const float cnt = counts[k];
    const float raw = 0.999f * ema_count[k] + 0.001f * cnt;
    const float p = cnt * (1.0f / 65536.0f);
    const float term = p * logf(p + 1e-10f);

    float v1 = raw, v2 = term;
#pragma unroll
    for (int off = 32; off; off >>= 1) {
        v1 += __shfl_down(v1, off, 64);
        v2 += __shfl_down(v2, off, 64);
    }
    __shared__ float r1[16], r2[16];
    __shared__ float s_n, s_plog;
    if ((k & 63) == 0) { r1[k >> 6] = v1; r2[k >> 6] = v2; }
    __syncthreads();
    if (k < 64) {
        float a = (k < 16) ? r1[k] : 0.0f;
        float b = (k < 16) ? r2[k] : 0.0f;
#pragma unroll
        for (int off = 8; off; off >>= 1) {
            a += __shfl_down(a, off, 64);
            b += __shfl_down(b, off, 64);
        }
        if (k == 0) { s_n = a; s_plog = b; }
    }
    __syncthreads();

    const float n = s_n;
    const float smoothed = (raw + 1e-5f) / (n + 1024.0f * 1e-5f) * n;
    out[NC_OFF + k] = smoothed;
    out[NU_OFF + k] = (usage[k] + (cnt > 0.0f ? 1.0f : 0.0f)) * 0.5f;
    if (k == 0) {
        const float lm = loss_sum[0] * (1.0f / 4194304.0f);
        out[SC_OFF + 0] = 0.25f * lm;    // commitment_loss
        out[SC_OFF + 1] = lm;            // codebook_loss
        out[SC_OFF + 2] = expf(-s_plog); // perplexity
    }
}

// Segment-sum via scan-gather + fused EMA epilogue: block k sums x rows of
// tokens with idx==k (ascending-token order == jax.ops.segment_sum), then
// wave 0 applies the EMA and writes new_weight / new_embedding directly.
__global__ __launch_bounds__(512) void gather_kernel(
    const float* __restrict__ x, const int* __restrict__ idx,
    const float* __restrict__ ema_weight, const float* __restrict__ out_nc,
    float* __restrict__ new_weight, float* __restrict__ new_embedding) {
    const int k    = blockIdx.x;          // code
    const int wave = threadIdx.x >> 6;    // 0..7
    const int lane = threadIdx.x & 63;    // dimension

    float acc = 0.0f;
    const int begin = wave * (N_TOK / 8);
    const int end   = begin + (N_TOK / 8);
    for (int base = begin; base < end; base += 128) {
        int mi0 = idx[base + lane];
        int mi1 = idx[base + 64 + lane];
        unsigned long long m0 = __ballot(mi0 == k);
        unsigned long long m1 = __ballot(mi1 == k);
        while (m0) {
            int b = __ffsll((long long)m0) - 1;
            m0 &= m0 - 1;
            acc += x[(size_t)(base + b) * 64 + lane];
        }
        while (m1) {
            int b = __ffsll((long long)m1) - 1;
            m1 &= m1 - 1;
            acc += x[(size_t)(base + 64 + b) * 64 + lane];
        }
    }

    __shared__ float red[8][64];
    red[wave][lane] = acc;
    __syncthreads();
    if (wave == 0) {
        float s = red[0][lane];
#pragma unroll
        for (int w = 1; w < 8; ++w) s += red[w][lane];
        const float nc = out_nc[k];                 // uniform scalar load
        float w = 0.999f * ema_weight[(size_t)k * 64 + lane] + 0.001f * s;
        new_weight[(size_t)k * 64 + lane] = w;
        new_embedding[(size_t)k * 64 + lane] = w / nc;
    }
}

extern "C" void kernel_launch(void* const* d_in, const int* in_sizes, int n_in,
                              void* d_out, int out_size, void* d_ws, size_t ws_size,
                              hipStream_t stream) {
    const float* x          = (const float*)d_in[0];
    const float* emb        = (const float*)d_in[1];
    const float* ema_count  = (const float*)d_in[2];
    const float* ema_weight = (const float*)d_in[3];
    const float* usage      = (const float*)d_in[4];
    float* out = (float*)d_out;
    float* ws  = (float*)d_ws;

    float* counts = ws + WS_COUNTS;
    float* loss   = ws + WS_LOSS;
    int*   idx    = (int*)(ws + WS_IDX);
    float* ps     = ws + WS_PS;
    int*   pi     = (int*)(ws + WS_PI);

    // ws is re-poisoned to 0xAA before every timed launch -> zero the
    // atomic regions (counts + loss). Everything else is fully written.
    hipMemsetAsync(ws, 0, 1025 * sizeof(float), stream);

    assign_kernel<<<2048, 256, 0, stream>>>(x, emb, ps, pi);
    merge_kernel<<<256, 256, 0, stream>>>(x, emb, ps, pi, counts, idx, loss,
                                          out + Q_OFF);
    finalize1<<<1, 1024, 0, stream>>>(counts, loss, ema_count, usage, out);
    gather_kernel<<<1024, 512, 0, stream>>>(x, idx, ema_weight, out + NC_OFF,
                                            out + NW_OFF, out + NE_OFF);
}

// Round 11
// 322.857 us; speedup vs baseline: 8.4094x; 8.4094x over previous
//
#include <hip/hip_runtime.h>

// ---------------------------------------------------------------------------
// VQEmbeddingEMA forward on MI355X (gfx950), fp32.
//   N = 32*2048 = 65536 tokens, D = 64, K = 1024 codes.
// Round 11: register-blocked LDS-tiled GEMM. Block = 64 tokens x all codes;
// per-thread 4x4 acc + float4 fragments (~50 hot VGPR; no 64-float arrays --
// rounds 8/10 proved those spill). x tile staged once, 16 e-tiles streamed
// from L2. XOR-swizzled LDS (slot = j ^ (row&7), row = w*32+c*8+grp so
// simultaneous rows differ in low 3 bits) -> conflict-free ds_read_b128.
// Tie-aware argmin everywhere. merge_kernel fused away.
// ---------------------------------------------------------------------------

#define N_TOK   65536
#define KCODES  1024

#define Q_OFF   0
#define SC_OFF  4194304
#define NE_OFF  4194307
#define NC_OFF  4259843
#define NW_OFF  4260867
#define NU_OFF  4326403

// ws layout (floats)
#define WS_COUNTS 0              // [1024]  (atomic, zeroed)
#define WS_LOSS   1024           // [1]     (atomic, zeroed)
#define WS_HN     1028           // [1024]
#define WS_IDX    2052           // [65536] int

// 0.5 * |e_k|^2 per code
__global__ __launch_bounds__(256) void hn_kernel(const float* __restrict__ emb,
                                                 float* __restrict__ hn) {
    int k = blockIdx.x * 256 + threadIdx.x;   // grid 4x256 -> 1024
    const float4* e4 = reinterpret_cast<const float4*>(emb) + (size_t)k * 16;
    float4 a = make_float4(0.f, 0.f, 0.f, 0.f);
#pragma unroll
    for (int i = 0; i < 16; ++i) {
        float4 e = e4[i];
        a.x = fmaf(e.x, e.x, a.x);
        a.y = fmaf(e.y, e.y, a.y);
        a.z = fmaf(e.z, e.z, a.z);
        a.w = fmaf(e.w, e.w, a.w);
    }
    hn[k] = 0.5f * ((a.x + a.y) + (a.z + a.w));
}

// Block b: tokens [b*64, b*64+64) vs all 1024 codes.
// 256 thr = 4 waves (wx = token-half, wy = code-half); lane: tg=lane&7 (token
// group), cg=lane>>3 (code group). Thread tile: 4 tokens x 4 codes.
// row_x(t) = wx*32 + t*8 + tg ; row_e(c) = wy*32 + c*8 + cg.
// LDS float4 slot for (row, j): row*16 + (j ^ (row&7)); row&7 = tg (or cg).
__global__ __launch_bounds__(256, 4) void assign_fused(
    const float* __restrict__ x, const float* __restrict__ emb,
    const float* __restrict__ hn_g, float* __restrict__ counts,
    float* __restrict__ loss_sum, int* __restrict__ idx,
    float* __restrict__ qout) {
    const int b    = blockIdx.x;
    const int tid  = threadIdx.x;
    const int lane = tid & 63;
    const int wid  = tid >> 6;       // 0..3
    const int wx   = wid & 1;        // token half
    const int wy   = wid >> 1;       // code half
    const int tg   = lane & 7;
    const int cg   = lane >> 3;

    __shared__ float4 sx4[1024];     // 64 tokens x 16 f4, swizzled (16 KB)
    __shared__ float4 se4[1024];     // 64 codes  x 16 f4, swizzled (16 KB)
    __shared__ float  shn[64];

    const float4* __restrict__ gx4 =
        reinterpret_cast<const float4*>(x) + (size_t)b * 1024;
    const float4* __restrict__ ge4 = reinterpret_cast<const float4*>(emb);

    // stage x tile once (coalesced; swizzled store)
#pragma unroll
    for (int i = 0; i < 4; ++i) {
        int f = i * 256 + tid;
        int r = f >> 4, j = f & 15;
        sx4[r * 16 + (j ^ (r & 7))] = gx4[f];
    }

    int rowx[4], rowe[4];
#pragma unroll
    for (int t = 0; t < 4; ++t) rowx[t] = wx * 32 + t * 8 + tg;
#pragma unroll
    for (int c = 0; c < 4; ++c) rowe[c] = wy * 32 + c * 8 + cg;

    float best[4] = {3.0e38f, 3.0e38f, 3.0e38f, 3.0e38f};
    int   bidx[4] = {0, 0, 0, 0};

    for (int et = 0; et < 16; ++et) {
        const int kbase = et * 64;
        __syncthreads();             // previous tile's reads complete
#pragma unroll
        for (int i = 0; i < 4; ++i) {
            int f = i * 256 + tid;
            int r = f >> 4, j = f & 15;
            se4[r * 16 + (j ^ (r & 7))] = ge4[(size_t)kbase * 16 + f];
        }
        if (tid < 64) shn[tid] = hn_g[kbase + tid];
        __syncthreads();

        float acc[4][4];
#pragma unroll
        for (int t = 0; t < 4; ++t)
#pragma unroll
            for (int c = 0; c < 4; ++c) acc[t][c] = 0.0f;

#pragma unroll
        for (int j = 0; j < 16; ++j) {
            float4 xf[4], ef[4];
#pragma unroll
            for (int t = 0; t < 4; ++t) xf[t] = sx4[rowx[t] * 16 + (j ^ tg)];
#pragma unroll
            for (int c = 0; c < 4; ++c) ef[c] = se4[rowe[c] * 16 + (j ^ cg)];
#pragma unroll
            for (int t = 0; t < 4; ++t)
#pragma unroll
                for (int c = 0; c < 4; ++c) {
                    acc[t][c] = fmaf(xf[t].x, ef[c].x, acc[t][c]);
                    acc[t][c] = fmaf(xf[t].y, ef[c].y, acc[t][c]);
                    acc[t][c] = fmaf(xf[t].z, ef[c].z, acc[t][c]);
                    acc[t][c] = fmaf(xf[t].w, ef[c].w, acc[t][c]);
                }
        }

#pragma unroll
        for (int c = 0; c < 4; ++c) {
            const float h    = shn[rowe[c]];
            const int   code = kbase + rowe[c];
#pragma unroll
            for (int t = 0; t < 4; ++t) {
                float s = h - acc[t][c];   // argmin_k 0.5|e|^2 - x.e
                if (s < best[t] || (s == best[t] && code < bidx[t])) {
                    best[t] = s; bidx[t] = code;
                }
            }
        }
    }

    // ---- cross-thread merge (cand buffers alias se4; safe after sync) ----
    __syncthreads();
    float* cand_s = reinterpret_cast<float*>(se4);        // [64][16]
    int*   cand_i = reinterpret_cast<int*>(se4) + 1024;   // [64][16]
    int*   sbi    = reinterpret_cast<int*>(se4) + 2048;   // [64]
    const int col = wy * 8 + cg;
#pragma unroll
    for (int t = 0; t < 4; ++t) {
        cand_s[rowx[t] * 16 + col] = best[t];
        cand_i[rowx[t] * 16 + col] = bidx[t];
    }
    __syncthreads();
    if (tid < 64) {
        float bs = cand_s[tid * 16];
        int   bi = cand_i[tid * 16];
#pragma unroll
        for (int q = 1; q < 16; ++q) {
            float s2 = cand_s[tid * 16 + q];
            int   i2 = cand_i[tid * 16 + q];
            if (s2 < bs || (s2 == bs && i2 < bi)) { bs = s2; bi = i2; }
        }
        sbi[tid] = bi;
        idx[b * 64 + tid] = bi;
        atomicAdd(&counts[bi], 1.0f);
    }
    __syncthreads();

    // ---- fused epilogue: quantized write + loss ----
    const int tok_in = tid >> 2, p4 = tid & 3;
    const int bi = sbi[tok_in];
    float4* q4 = reinterpret_cast<float4*>(qout) +
                 (size_t)(b * 64 + tok_in) * 16 + p4 * 4;
    float lsum = 0.0f;
#pragma unroll
    for (int i = 0; i < 4; ++i) {
        float4 ev = ge4[(size_t)bi * 16 + p4 * 4 + i];
        float4 xv = sx4[tok_in * 16 + ((p4 * 4 + i) ^ (tok_in & 7))];
        q4[i] = ev;
        float d0 = xv.x - ev.x; lsum = fmaf(d0, d0, lsum);
        float d1 = xv.y - ev.y; lsum = fmaf(d1, d1, lsum);
        float d2 = xv.z - ev.z; lsum = fmaf(d2, d2, lsum);
        float d3 = xv.w - ev.w; lsum = fmaf(d3, d3, lsum);
    }
#pragma unroll
    for (int off = 32; off; off >>= 1) lsum += __shfl_down(lsum, off, 64);
    if (lane == 0) atomicAdd(loss_sum, lsum);
}

// counts-based outputs: new_count, new_usage, scalars (one block, k = tid).
// Runs BEFORE gather (gather reads out[NC_OFF+k]).
__global__ __launch_bounds__(1024) void finalize1(
    const float* __restrict__ counts, const float* __restrict__ loss_sum,
    const float* __restrict__ ema_count, const float* __restrict__ usage,
    float* __restrict__ out) {
    const int k = threadIdx.x;
    const float cnt = counts[k];
    const float raw = 0.999f * ema_count[k] + 0.001f * cnt;
    const float p = cnt * (1.0f / 65536.0f);
    const float term = p * logf(p + 1e-10f);

    float v1 = raw, v2 = term;
#pragma unroll
    for (int off = 32; off; off >>= 1) {
        v1 += __shfl_down(v1, off, 64);
        v2 += __shfl_down(v2, off, 64);
    }
    __shared__ float r1[16], r2[16];
    __shared__ float s_n, s_plog;
    if ((k & 63) == 0) { r1[k >> 6] = v1; r2[k >> 6] = v2; }
    __syncthreads();
    if (k < 64) {
        float a = (k < 16) ? r1[k] : 0.0f;
        float b = (k < 16) ? r2[k] : 0.0f;
#pragma unroll
        for (int off = 8; off; off >>= 1) {
            a += __shfl_down(a, off, 64);
            b += __shfl_down(b, off, 64);
        }
        if (k == 0) { s_n = a; s_plog = b; }
    }
    __syncthreads();

    const float n = s_n;
    const float smoothed = (raw + 1e-5f) / (n + 1024.0f * 1e-5f) * n;
    out[NC_OFF + k] = smoothed;
    out[NU_OFF + k] = (usage[k] + (cnt > 0.0f ? 1.0f : 0.0f)) * 0.5f;
    if (k == 0) {
        const float lm = loss_sum[0] * (1.0f / 4194304.0f);
        out[SC_OFF + 0] = 0.25f * lm;    // commitment_loss
        out[SC_OFF + 1] = lm;            // codebook_loss
        out[SC_OFF + 2] = expf(-s_plog); // perplexity
    }
}

// Segment-sum via scan-gather + fused EMA epilogue: block k sums x rows of
// tokens with idx==k (ascending-token order == jax.ops.segment_sum), then
// wave 0 applies the EMA and writes new_weight / new_embedding directly.
__global__ __launch_bounds__(512) void gather_kernel(
    const float* __restrict__ x, const int* __restrict__ idx,
    const float* __restrict__ ema_weight, const float* __restrict__ out_nc,
    float* __restrict__ new_weight, float* __restrict__ new_embedding) {
    const int k    = blockIdx.x;          // code
    const int wave = threadIdx.x >> 6;    // 0..7
    const int lane = threadIdx.x & 63;    // dimension

    float acc = 0.0f;
    const int begin = wave * (N_TOK / 8);
    const int end   = begin + (N_TOK / 8);
    for (int base = begin; base < end; base += 128) {
        int mi0 = idx[base + lane];
        int mi1 = idx[base + 64 + lane];
        unsigned long long m0 = __ballot(mi0 == k);
        unsigned long long m1 = __ballot(mi1 == k);
        while (m0) {
            int t = __ffsll((long long)m0) - 1;
            m0 &= m0 - 1;
            acc += x[(size_t)(base + t) * 64 + lane];
        }
        while (m1) {
            int t = __ffsll((long long)m1) - 1;
            m1 &= m1 - 1;
            acc += x[(size_t)(base + 64 + t) * 64 + lane];
        }
    }

    __shared__ float red[8][64];
    red[wave][lane] = acc;
    __syncthreads();
    if (wave == 0) {
        float s = red[0][lane];
#pragma unroll
        for (int w = 1; w < 8; ++w) s += red[w][lane];
        const float nc = out_nc[k];                 // uniform scalar load
        float w = 0.999f * ema_weight[(size_t)k * 64 + lane] + 0.001f * s;
        new_weight[(size_t)k * 64 + lane] = w;
        new_embedding[(size_t)k * 64 + lane] = w / nc;
    }
}

extern "C" void kernel_launch(void* const* d_in, const int* in_sizes, int n_in,
                              void* d_out, int out_size, void* d_ws, size_t ws_size,
                              hipStream_t stream) {
    const float* x          = (const float*)d_in[0];
    const float* emb        = (const float*)d_in[1];
    const float* ema_count  = (const float*)d_in[2];
    const float* ema_weight = (const float*)d_in[3];
    const float* usage      = (const float*)d_in[4];
    float* out = (float*)d_out;
    float* ws  = (float*)d_ws;

    float* counts = ws + WS_COUNTS;
    float* loss   = ws + WS_LOSS;
    float* hn     = ws + WS_HN;
    int*   idx    = (int*)(ws + WS_IDX);

    // ws is re-poisoned to 0xAA before every timed launch -> zero the
    // atomic regions (counts + loss). Everything else is fully written.
    hipMemsetAsync(ws, 0, 1025 * sizeof(float), stream);

    hn_kernel<<<4, 256, 0, stream>>>(emb, hn);
    assign_fused<<<1024, 256, 0, stream>>>(x, emb, hn, counts, loss, idx,
                                           out + Q_OFF);
    finalize1<<<1, 1024, 0, stream>>>(counts, loss, ema_count, usage, out);
    gather_kernel<<<1024, 512, 0, stream>>>(x, idx, ema_weight, out + NC_OFF,
                                            out + NW_OFF, out + NE_OFF);
}